// Round 1
// baseline (49.270 us; speedup 1.0000x reference)
//
#include <hip/hip_runtime.h>
#include <math.h>

#ifndef M_PI
#define M_PI 3.14159265358979323846
#endif

#define NH 32   // N/2 modes

// One block per h. 256 threads; thread tid owns l = tid + j*256, j=0..L/256-1.
// State per mode: y = C_eff * exp(dtA*l); per step y *= w, w = exp(dtA*256).
// acc = sum Re(y) (factor 2 folded into C_eff).
__global__ __launch_bounds__(256, 2) void s4d_kernel(
    const float* __restrict__ log_dt,
    const float* __restrict__ Cv,          // (H, 32, 2)
    const float* __restrict__ log_A_real,  // (H, 32)
    const float* __restrict__ A_imag,      // (H, 32)
    float* __restrict__ Kout,              // (H, L)
    int L)
{
    const int h = blockIdx.x;
    const int tid = threadIdx.x;
    const int stride = blockDim.x;   // 256
    const int steps = L / stride;    // 16

    __shared__ float s_ce[NH][2];  // C_eff (x2 folded)
    __shared__ float s_w[NH][2];   // step multiplier exp(dtA*stride)
    __shared__ float s_da[NH][2];  // dar, dai

    if (tid < NH) {
        const int n = tid;
        const float dt = expf(log_dt[h]);
        const float Ar = -expf(log_A_real[h * NH + n]);
        const float Ai = A_imag[h * NH + n];
        const float dar = Ar * dt;
        const float dai = Ai * dt;

        // exp(dtA) - 1
        float er = expf(dar);
        float sn, cs;
        sincosf(dai, &sn, &cs);
        float edr = er * cs - 1.0f;
        float edi = er * sn;

        // (exp(dtA)-1)/A  via conj(A)/|A|^2
        float inv = 1.0f / (Ar * Ar + Ai * Ai);
        float fr = (edr * Ar + edi * Ai) * inv;
        float fi = (edi * Ar - edr * Ai) * inv;

        // C_eff = 2 * Cc * f   (factor 2 of the final K folded here)
        float cr = Cv[(h * NH + n) * 2 + 0];
        float ci = Cv[(h * NH + n) * 2 + 1];
        s_ce[n][0] = 2.0f * (cr * fr - ci * fi);
        s_ce[n][1] = 2.0f * (cr * fi + ci * fr);

        // w = exp(dtA * stride); angle reduced in double so 16-step
        // recurrence phase drift stays ~1e-5 rad.
        double angd = fmod((double)dai * (double)stride, 2.0 * M_PI);
        float es = expf(dar * (float)stride);
        float ws, wc;
        sincosf((float)angd, &ws, &wc);
        s_w[n][0] = es * wc;
        s_w[n][1] = es * ws;

        s_da[n][0] = dar;
        s_da[n][1] = dai;
    }
    __syncthreads();

    float yr[NH], yi[NH], wr[NH], wi[NH];
    const float t0 = (float)tid;
    #pragma unroll
    for (int n = 0; n < NH; ++n) {
        float e0 = expf(s_da[n][0] * t0);
        float sn, cs;
        sincosf(s_da[n][1] * t0, &sn, &cs);
        float zr = e0 * cs, zi = e0 * sn;
        float cr = s_ce[n][0], ci = s_ce[n][1];
        yr[n] = cr * zr - ci * zi;
        yi[n] = cr * zi + ci * zr;
        wr[n] = s_w[n][0];
        wi[n] = s_w[n][1];
    }

    float* out = Kout + (size_t)h * (size_t)L + tid;
    for (int j = 0; j < steps; ++j) {
        float a0 = 0.f, a1 = 0.f, a2 = 0.f, a3 = 0.f;
        #pragma unroll
        for (int n = 0; n < NH; n += 4) {
            a0 += yr[n + 0];
            a1 += yr[n + 1];
            a2 += yr[n + 2];
            a3 += yr[n + 3];
            #pragma unroll
            for (int q = 0; q < 4; ++q) {
                float t = fmaf(yr[n + q], wr[n + q], -(yi[n + q] * wi[n + q]));
                float u = fmaf(yr[n + q], wi[n + q],  (yi[n + q] * wr[n + q]));
                yr[n + q] = t;
                yi[n + q] = u;
            }
        }
        out[(size_t)j * stride] = (a0 + a1) + (a2 + a3);
    }
}

extern "C" void kernel_launch(void* const* d_in, const int* in_sizes, int n_in,
                              void* d_out, int out_size, void* d_ws, size_t ws_size,
                              hipStream_t stream) {
    // inputs: [0]=L (int scalar), [1]=log_dt (H,), [2]=C (H,32,2),
    //         [3]=log_A_real (H,32), [4]=A_imag (H,32)
    const float* log_dt     = (const float*)d_in[1];
    const float* Cv         = (const float*)d_in[2];
    const float* log_A_real = (const float*)d_in[3];
    const float* A_imag     = (const float*)d_in[4];
    float* Kout = (float*)d_out;

    const int Hn = in_sizes[1];          // 1024
    const int L  = out_size / Hn;        // 4096

    dim3 grid(Hn), block(256);
    hipLaunchKernelGGL(s4d_kernel, grid, block, 0, stream,
                       log_dt, Cv, log_A_real, A_imag, Kout, L);
}

// Round 2
// 29.759 us; speedup vs baseline: 1.6556x; 1.6556x over previous
//
#include <hip/hip_runtime.h>
#include <math.h>

#ifndef M_PI
#define M_PI 3.14159265358979323846
#endif

#define NH 32     // total modes (N/2)
#define NHALF 16  // modes per thread (lane-split)

typedef float v2f __attribute__((ext_vector_type(2)));

// One block per h, 256 threads (4 waves). Within a wave: lanes 0-31 handle
// modes 0-15, lanes 32-63 handle modes 16-31, for the SAME 32 l-positions.
// Thread's l sequence: l0 + j*128, l0 = wave*32 + (lane&31), j = 0..31.
// Recurrence: y *= w where w = exp(dtA*128); K(l) = sum Re(y) combined
// across the two lane-halves with one shfl_xor(32).
__global__ __launch_bounds__(256, 4) void s4d_kernel(
    const float* __restrict__ log_dt,
    const float* __restrict__ Cv,          // (H, 32, 2)
    const float* __restrict__ log_A_real,  // (H, 32)
    const float* __restrict__ A_imag,      // (H, 32)
    float* __restrict__ Kout,              // (H, L)
    int L)
{
    const int h   = blockIdx.x;
    const int tid = threadIdx.x;

    __shared__ float s_ce[NH][2];  // C_eff (x2 of final K folded in)
    __shared__ float s_w [NH][2];  // w  = exp(dtA*128)
    __shared__ float s_v [NH][2];  // v  = i*w = (-wi, wr)
    __shared__ float s_da[NH][2];  // (dar, dai)

    // ---- Phase A: per-(h,n) uniforms, 32 threads, libm is fine here ----
    if (tid < NH) {
        const int n = tid;
        const float dt  = __expf(log_dt[h]);
        const float Ar  = -__expf(log_A_real[h * NH + n]);
        const float Ai  = A_imag[h * NH + n];
        const float dar = Ar * dt;
        const float dai = Ai * dt;

        // C_eff = 2 * C * (exp(dtA) - 1) / A
        float er = expf(dar);
        float sn, cs;
        __sincosf(dai, &sn, &cs);          // |dai| <= ~9.8, fast path ok
        float edr = er * cs - 1.0f;
        float edi = er * sn;
        float inv = 1.0f / (Ar * Ar + Ai * Ai);
        float fr  = (edr * Ar + edi * Ai) * inv;
        float fi  = (edi * Ar - edr * Ai) * inv;
        float cr  = Cv[(h * NH + n) * 2 + 0];
        float ci  = Cv[(h * NH + n) * 2 + 1];
        s_ce[n][0] = 2.0f * (cr * fr - ci * fi);
        s_ce[n][1] = 2.0f * (cr * fi + ci * fr);

        // w = exp(dtA * 128); angle reduced in double (|dai*128| up to ~1250 rad)
        double angd = fmod((double)dai * 128.0, 2.0 * M_PI);
        float es = __expf(dar * 128.0f);
        float ws, wc;
        __sincosf((float)angd, &ws, &wc);
        s_w[n][0] = es * wc;  s_w[n][1] = es * ws;
        s_v[n][0] = -es * ws; s_v[n][1] = es * wc;

        s_da[n][0] = dar; s_da[n][1] = dai;
    }
    __syncthreads();

    // ---- Phase B: per-thread state init (HW trans ops only) ----
    const int lane = tid & 63;
    const int half = lane >> 5;                 // which 16 modes
    const int l0   = (tid >> 6) * 32 + (lane & 31);
    const float l0f = (float)l0;

    v2f y[NHALF], w[NHALF], v[NHALF];
    #pragma unroll
    for (int m = 0; m < NHALF; ++m) {
        const int n = half * NHALF + m;
        float dar = s_da[n][0], dai = s_da[n][1];
        float e0 = __expf(dar * l0f);           // |dar*l0| <= ~6.4
        float sn, cs;
        __sincosf(dai * l0f, &sn, &cs);         // phase err ~1e-4 rad, ok
        float zr = e0 * cs, zi = e0 * sn;
        float cr = s_ce[n][0], ci = s_ce[n][1];
        y[m][0] = cr * zr - ci * zi;
        y[m][1] = cr * zi + ci * zr;
        w[m][0] = s_w[n][0]; w[m][1] = s_w[n][1];
        v[m][0] = s_v[n][0]; v[m][1] = s_v[n][1];
    }

    // ---- Main loop: 32 steps of 128 l's per block ----
    float* out = Kout + (size_t)h * (size_t)L + l0;
    const int steps = L >> 7;                   // L/128 = 32
    #pragma unroll 1
    for (int j = 0; j < steps; ++j) {
        float a0 = 0.f, a1 = 0.f, a2 = 0.f, a3 = 0.f;
        #pragma unroll
        for (int m = 0; m < NHALF; m += 4) {
            a0 += y[m + 0][0];
            a1 += y[m + 1][0];
            a2 += y[m + 2][0];
            a3 += y[m + 3][0];
            #pragma unroll
            for (int q = 0; q < 4; ++q) {
                // complex y *= w in 2 VOP3P ops:
                // t   = (yr*wr, yr*wi)
                // y'  = (yi*(-wi) + t.lo, yi*wr + t.hi)
                v2f t;
                asm("v_pk_mul_f32 %0, %1, %2 op_sel:[0,0] op_sel_hi:[0,1]"
                    : "=v"(t) : "v"(y[m + q]), "v"(w[m + q]));
                asm("v_pk_fma_f32 %0, %1, %2, %3 op_sel:[1,0,0] op_sel_hi:[1,1,1]"
                    : "=v"(y[m + q]) : "v"(y[m + q]), "v"(v[m + q]), "v"(t));
            }
        }
        float acc = (a0 + a1) + (a2 + a3);
        float tot = acc + __shfl_xor(acc, 32, 64);
        if (half == 0) out[(size_t)j * 128] = tot;
    }
}

extern "C" void kernel_launch(void* const* d_in, const int* in_sizes, int n_in,
                              void* d_out, int out_size, void* d_ws, size_t ws_size,
                              hipStream_t stream) {
    // inputs: [0]=L (int scalar), [1]=log_dt (H,), [2]=C (H,32,2),
    //         [3]=log_A_real (H,32), [4]=A_imag (H,32)
    const float* log_dt     = (const float*)d_in[1];
    const float* Cv         = (const float*)d_in[2];
    const float* log_A_real = (const float*)d_in[3];
    const float* A_imag     = (const float*)d_in[4];
    float* Kout = (float*)d_out;

    const int Hn = in_sizes[1];          // 1024
    const int L  = out_size / Hn;        // 4096

    dim3 grid(Hn), block(256);
    hipLaunchKernelGGL(s4d_kernel, grid, block, 0, stream,
                       log_dt, Cv, log_A_real, A_imag, Kout, L);
}

// Round 3
// 24.882 us; speedup vs baseline: 1.9801x; 1.1960x over previous
//
#include <hip/hip_runtime.h>
#include <math.h>

#define NH 32     // total modes (N/2)
#define NHALF 16  // modes per thread (lane-split)
#define BLK_L 2048  // l-span per block; power of 2 so dai*BLK_L is exact in fp32

typedef float v2f __attribute__((ext_vector_type(2)));

// Reduce x mod 2*pi to [-pi, pi] with 2-term float Cody-Waite.
// PI2_HI = 6.28125 has a 7-bit mantissa -> k*PI2_HI exact for k < 2^16.
// Total error ~3e-7 rad for |x| <= ~2.2e4.
__device__ __forceinline__ float reduce2pi(float x) {
    const float INV2PI = 0.15915494309189535f;
    const float PI2_HI = 6.28125f;
    const float PI2_LO = 1.9353071795864769e-3f;
    float k = rintf(x * INV2PI);
    float r = fmaf(-k, PI2_HI, x);
    r = fmaf(-k, PI2_LO, r);
    return r;
}

// Grid: 2 blocks per h (blockIdx = h*2 + blk); each block covers
// l in [blk*2048, blk*2048+2048), 16 steps of 128 l's.
// 256 threads (4 waves). Lanes 0-31: modes 0-15; lanes 32-63: modes 16-31,
// for the same 32 l positions. Thread's l = blk*2048 + l0 + j*128.
// Recurrence y *= w, w = exp(dtA*128); K(l) = sum Re(y), halves combined
// by one shfl_xor(32). Block-base phase exp(dtA*blk*2048) folded into C_eff.
__global__ __launch_bounds__(256, 5) void s4d_kernel(
    const float* __restrict__ log_dt,
    const float* __restrict__ Cv,          // (H, 32, 2)
    const float* __restrict__ log_A_real,  // (H, 32)
    const float* __restrict__ A_imag,      // (H, 32)
    float* __restrict__ Kout,              // (H, L)
    int L)
{
    const int bid = blockIdx.x;
    const int h   = bid >> 1;
    const int blk = bid & 1;
    const int tid = threadIdx.x;

    __shared__ float s_ce[NH][2];  // C_eff * exp(dtA*blk*2048)  (x2 folded)
    __shared__ float s_w [NH][2];  // w = exp(dtA*128)
    __shared__ float s_da[NH][2];  // (dar, dai)

    // ---- Phase A: per-(h,n) uniforms, 32 threads, no f64, no libm ----
    if (tid < NH) {
        const int n = tid;
        const float dt  = __expf(log_dt[h]);
        const float Ar  = -__expf(log_A_real[h * NH + n]);
        const float Ai  = A_imag[h * NH + n];
        const float dar = Ar * dt;
        const float dai = Ai * dt;

        // C_eff = 2 * C * (exp(dtA) - 1) / A
        float er = __expf(dar);
        float sn, cs;
        __sincosf(dai, &sn, &cs);          // |dai| <= ~9.8
        float edr = fmaf(er, cs, -1.0f);
        float edi = er * sn;
        float inv = 1.0f / fmaf(Ar, Ar, Ai * Ai);
        float fr  = (edr * Ar + edi * Ai) * inv;
        float fi  = (edi * Ar - edr * Ai) * inv;
        float cr  = Cv[(h * NH + n) * 2 + 0];
        float ci  = Cv[(h * NH + n) * 2 + 1];
        float cer = 2.0f * (cr * fr - ci * fi);
        float cei = 2.0f * (cr * fi + ci * fr);

        // fold block-base rotation: ce *= exp(dtA * blk*2048)
        float Bf  = (float)(blk * BLK_L);   // 0 or 2048: dai*Bf exact
        float eB  = __expf(dar * Bf);       // may underflow to 0: mode dead, ok
        float thB = reduce2pi(dai * Bf);
        float sB, cB;
        __sincosf(thB, &sB, &cB);
        float br = eB * cB, bi = eB * sB;
        s_ce[n][0] = cer * br - cei * bi;
        s_ce[n][1] = cer * bi + cei * br;

        // step multiplier w = exp(dtA*128); dai*128 exact (power of 2)
        float ew  = __expf(dar * 128.0f);
        float thw = reduce2pi(dai * 128.0f);
        float sw, cw;
        __sincosf(thw, &sw, &cw);
        s_w[n][0] = ew * cw;
        s_w[n][1] = ew * sw;

        s_da[n][0] = dar;
        s_da[n][1] = dai;
    }
    __syncthreads();

    // ---- Phase B: per-thread state init (HW trans ops only) ----
    const int lane = tid & 63;
    const int half = lane >> 5;                 // which 16 modes
    const int l0   = (tid >> 6) * 32 + (lane & 31);   // 0..127
    const float l0f = (float)l0;

    v2f y[NHALF], w[NHALF];
    #pragma unroll
    for (int m = 0; m < NHALF; ++m) {
        const int n = half * NHALF + m;
        float dar = s_da[n][0], dai = s_da[n][1];
        float e0 = __expf(dar * l0f);
        float sn, cs;
        __sincosf(dai * l0f, &sn, &cs);         // |ang| <= ~1240 rad, ok (R2)
        float zr = e0 * cs, zi = e0 * sn;
        float cr = s_ce[n][0], ci = s_ce[n][1];
        y[m][0] = cr * zr - ci * zi;
        y[m][1] = cr * zi + ci * zr;
        w[m][0] = s_w[n][0];
        w[m][1] = s_w[n][1];
    }

    // ---- Main loop: 16 steps of 128 l's ----
    float* out = Kout + (size_t)h * (size_t)L + blk * BLK_L + l0;
    #pragma unroll 2
    for (int j = 0; j < BLK_L / 128; ++j) {
        float a0 = 0.f, a1 = 0.f, a2 = 0.f, a3 = 0.f;
        #pragma unroll
        for (int m = 0; m < NHALF; m += 4) {
            a0 += y[m + 0][0];
            a1 += y[m + 1][0];
            a2 += y[m + 2][0];
            a3 += y[m + 3][0];
            #pragma unroll
            for (int q = 0; q < 4; ++q) {
                // complex y *= w in 2 VOP3P ops, negation via neg_lo:
                // t  = (yr*wr, yr*wi)
                // y' = (yi*(-wi) + t.lo, yi*wr + t.hi)
                v2f t;
                asm("v_pk_mul_f32 %0, %1, %2 op_sel:[0,0] op_sel_hi:[0,1]"
                    : "=v"(t) : "v"(y[m + q]), "v"(w[m + q]));
                asm("v_pk_fma_f32 %0, %1, %2, %3 op_sel:[1,1,0] op_sel_hi:[1,0,1] neg_lo:[0,1,0]"
                    : "=v"(y[m + q]) : "v"(y[m + q]), "v"(w[m + q]), "v"(t));
            }
        }
        float acc = (a0 + a1) + (a2 + a3);
        float tot = acc + __shfl_xor(acc, 32, 64);
        if (half == 0) out[(size_t)j * 128] = tot;
    }
}

extern "C" void kernel_launch(void* const* d_in, const int* in_sizes, int n_in,
                              void* d_out, int out_size, void* d_ws, size_t ws_size,
                              hipStream_t stream) {
    // inputs: [0]=L (int scalar), [1]=log_dt (H,), [2]=C (H,32,2),
    //         [3]=log_A_real (H,32), [4]=A_imag (H,32)
    const float* log_dt     = (const float*)d_in[1];
    const float* Cv         = (const float*)d_in[2];
    const float* log_A_real = (const float*)d_in[3];
    const float* A_imag     = (const float*)d_in[4];
    float* Kout = (float*)d_out;

    const int Hn = in_sizes[1];          // 1024
    const int L  = out_size / Hn;        // 4096

    dim3 grid(Hn * (L / BLK_L)), block(256);
    hipLaunchKernelGGL(s4d_kernel, grid, block, 0, stream,
                       log_dt, Cv, log_A_real, A_imag, Kout, L);
}